// Round 1
// baseline (936.908 us; speedup 1.0000x reference)
//
#include <hip/hip_runtime.h>
#include <cstdint>

using u16 = unsigned short;
using u32 = unsigned int;

typedef _Float16 h8 __attribute__((ext_vector_type(8)));
typedef _Float16 h4 __attribute__((ext_vector_type(4)));
typedef float f32x4 __attribute__((ext_vector_type(4)));

#define N_PER_B 175
#define NN 22400
#define DCOL 1024

// async global->LDS, 16B per lane; LDS dst is wave-uniform base + lane*16
__device__ __forceinline__ void gload16(const void* g, void* l) {
  void* gnc = const_cast<void*>(g);
  __builtin_amdgcn_global_load_lds(
      (__attribute__((address_space(1))) unsigned int*)gnc,
      (__attribute__((address_space(3))) unsigned int*)l, 16, 0, 0);
}

// ---------------- degree / CSR build ----------------

__global__ void degree_k(const int* __restrict__ es, const int* __restrict__ ed,
                         u32* __restrict__ dout, u32* __restrict__ din, int nE) {
  int e = blockIdx.x * 256 + threadIdx.x;
  if (e < nE) {
    atomicAdd(&dout[es[e]], 1u);
    atomicAdd(&din[ed[e]], 1u);
  }
}

__global__ void dinv_k(const u32* __restrict__ dout, const u32* __restrict__ din,
                       float* __restrict__ vo, float* __restrict__ vi) {
  int i = blockIdx.x * 256 + threadIdx.x;
  if (i < NN) {
    u32 a = dout[i]; if (a == 0u) a = 1u;
    u32 b = din[i];  if (b == 0u) b = 1u;
    vo[i] = rsqrtf((float)a);
    vi[i] = rsqrtf((float)b);
  }
}

__global__ __launch_bounds__(1024) void scan_k(const u32* __restrict__ deg,
                                               u32* __restrict__ off, int n) {
  __shared__ u32 buf[1024];
  __shared__ u32 carry;
  int tid = threadIdx.x;
  if (tid == 0) carry = 0u;
  __syncthreads();
  for (int base = 0; base < n; base += 1024) {
    u32 cb = carry;
    int i = base + tid;
    u32 v = (i < n) ? deg[i] : 0u;
    buf[tid] = v;
    __syncthreads();
    for (int s2 = 1; s2 < 1024; s2 <<= 1) {
      u32 t = (tid >= s2) ? buf[tid - s2] : 0u;
      __syncthreads();
      buf[tid] += t;
      __syncthreads();
    }
    u32 incl = buf[tid];
    if (i < n) off[i] = cb + incl - v;  // exclusive
    __syncthreads();
    if (tid == 1023) carry = cb + incl;
    __syncthreads();
  }
  if (tid == 0) off[n] = carry;
}

__global__ void scatter_k(const int* __restrict__ es, const int* __restrict__ ed,
                          const u32* __restrict__ off, u32* __restrict__ cur,
                          int* __restrict__ csr, int nE) {
  int e = blockIdx.x * 256 + threadIdx.x;
  if (e < nE) {
    int d = ed[e];
    u32 p = atomicAdd(&cur[d], 1u);
    csr[off[d] + p] = es[e];
  }
}

// ---------------- concat + layernorm -> fp16 node matrix ----------------

__global__ __launch_bounds__(256) void ln_k(const float* __restrict__ mh,
    const float* __restrict__ eh, const float* __restrict__ sh,
    const float* __restrict__ te, const float* __restrict__ sc,
    const float* __restrict__ bi, _Float16* __restrict__ x0) {
  int node = blockIdx.x;
  int b = node / N_PER_B;
  int p = node - b * N_PER_B;
  const float* row;
  int t;
  if (p < 100)      { row = mh + ((size_t)b * 100 + p) * 768;        t = 0; }
  else if (p < 150) { row = eh + ((size_t)b * 50 + (p - 100)) * 768; t = 1; }
  else              { row = sh + ((size_t)b * 25 + (p - 150)) * 768; t = 2; }
  int tid = threadIdx.x;
  const float* lp = (tid < 192) ? (row + tid * 4) : (te + t * 256 + (tid - 192) * 4);
  float4 v = *(const float4*)lp;
  float s = v.x + v.y + v.z + v.w;
  float q = v.x * v.x + v.y * v.y + v.z * v.z + v.w * v.w;
#pragma unroll
  for (int o = 32; o > 0; o >>= 1) { s += __shfl_down(s, o); q += __shfl_down(q, o); }
  __shared__ float red[8];
  int w = tid >> 6;
  if ((tid & 63) == 0) { red[w] = s; red[4 + w] = q; }
  __syncthreads();
  float ts = red[0] + red[1] + red[2] + red[3];
  float tq = red[4] + red[5] + red[6] + red[7];
  float mu = ts * (1.0f / 1024.0f);
  float var = tq * (1.0f / 1024.0f) - mu * mu;
  float r = rsqrtf(var + 1e-5f);
  int c = tid * 4;
  float4 g  = *(const float4*)(sc + c);
  float4 hb = *(const float4*)(bi + c);
  h4 o;
  o.x = (_Float16)((v.x - mu) * r * g.x + hb.x);
  o.y = (_Float16)((v.y - mu) * r * g.y + hb.y);
  o.z = (_Float16)((v.z - mu) * r * g.z + hb.z);
  o.w = (_Float16)((v.w - mu) * r * g.w + hb.w);
  *(h4*)(x0 + (size_t)node * DCOL + c) = o;
}

// ---------------- weight transpose fp32 [K][N] -> fp16 [N][K] ----------------

__global__ __launch_bounds__(256) void transpose_k(const float* __restrict__ W,
    _Float16* __restrict__ Wt, int K, int N) {
  __shared__ float tile[32][33];
  int n0 = blockIdx.x * 32, k0 = blockIdx.y * 32;
  int tx = threadIdx.x & 31, ty = threadIdx.x >> 5;  // 32 x 8
#pragma unroll
  for (int i = 0; i < 32; i += 8)
    tile[ty + i][tx] = W[(size_t)(k0 + ty + i) * N + n0 + tx];
  __syncthreads();
#pragma unroll
  for (int i = 0; i < 32; i += 8)
    Wt[(size_t)(n0 + ty + i) * K + k0 + tx] = (_Float16)tile[tx][ty + i];
}

// ---------------- CSR aggregation: agg[d] = dinv_in[d] * sum_src dinv_out[s]*x[s] ----------------

template<int ENT>
__global__ __launch_bounds__(256) void aggregate_k(const _Float16* __restrict__ x,
    const u32* __restrict__ off, const int* __restrict__ srcs,
    const float* __restrict__ dvo, const float* __restrict__ dvi,
    _Float16* __restrict__ out) {
  int blk = blockIdx.x;
  int d;
  if (ENT) { int b = blk / 50; d = b * N_PER_B + 100 + (blk - b * 50); }
  else d = blk;
  u32 s0 = off[d], s1 = off[d + 1];
  int c = threadIdx.x * 4;
  float a0 = 0.f, a1 = 0.f, a2 = 0.f, a3 = 0.f;
  for (u32 s = s0; s < s1; ++s) {
    int sn = srcs[s];
    float wv = dvo[sn];
    h4 u = *(const h4*)(x + (size_t)sn * DCOL + c);
    a0 += wv * (float)u.x;
    a1 += wv * (float)u.y;
    a2 += wv * (float)u.z;
    a3 += wv * (float)u.w;
  }
  float wi = dvi[d];
  h4 o;
  o.x = (_Float16)(a0 * wi);
  o.y = (_Float16)(a1 * wi);
  o.z = (_Float16)(a2 * wi);
  o.w = (_Float16)(a3 * wi);
  *(h4*)(out + (size_t)blk * DCOL + c) = o;
}

// ---------------- MFMA GEMM: C = A[M,K] * Bt[N,K]^T (+bias, epilogue) ----------------
// EPI 0: leaky_relu(C+bias) -> f16 out (ld N) ; EPI 1: C+bias -> f32 out (ld N)

template<int EPI>
__global__ __launch_bounds__(256, 2) void gemm_bt(const _Float16* __restrict__ A,
    const _Float16* __restrict__ Bt, const float* __restrict__ bias,
    _Float16* __restrict__ outh, float* __restrict__ outf, int N, int K) {
  __shared__ __align__(16) _Float16 sA[128 * 32];
  __shared__ __align__(16) _Float16 sB[128 * 32];
  int tid = threadIdx.x;
  int wave = tid >> 6, lane = tid & 63;
  int wm = wave & 1, wn = wave >> 1;
  int lane16 = lane & 15, quad = lane >> 4;
  int m0 = blockIdx.y * 128, n0 = blockIdx.x * 128;
  // staging: wave w stages tile rows [w*32, w*32+32) of both A and Bt.
  // per instr: 64 lanes * 16B = 16 rows x 64B (row-major BK=32 f16).
  int srow  = lane >> 2;          // 0..15
  int scolb = (lane & 3) * 16;    // 0/16/32/48 bytes into the 64B row
  const char* aBase = (const char*)(A  + (size_t)(m0 + wave * 32 + srow) * K) + scolb;
  const char* bBase = (const char*)(Bt + (size_t)(n0 + wave * 32 + srow) * K) + scolb;
  const size_t rowSkip = (size_t)16 * K * sizeof(_Float16);
  _Float16* lA0 = &sA[(wave * 2 + 0) * 512];
  _Float16* lA1 = &sA[(wave * 2 + 1) * 512];
  _Float16* lB0 = &sB[(wave * 2 + 0) * 512];
  _Float16* lB1 = &sB[(wave * 2 + 1) * 512];

  f32x4 acc[4][4];
  f32x4 zero = {0.f, 0.f, 0.f, 0.f};
#pragma unroll
  for (int i = 0; i < 4; ++i)
#pragma unroll
    for (int j = 0; j < 4; ++j) acc[i][j] = zero;

  for (int k0 = 0; k0 < K; k0 += 32) {
    __syncthreads();
    size_t kb = (size_t)k0 * sizeof(_Float16);
    gload16(aBase + kb,           lA0);
    gload16(aBase + kb + rowSkip, lA1);
    gload16(bBase + kb,           lB0);
    gload16(bBase + kb + rowSkip, lB1);
    __syncthreads();  // drains vmcnt before any wave reads LDS
    h8 af[4], bq[4];
#pragma unroll
    for (int mt = 0; mt < 4; ++mt)
      af[mt] = *(const h8*)&sA[(wm * 64 + mt * 16 + lane16) * 32 + quad * 8];
#pragma unroll
    for (int nt = 0; nt < 4; ++nt)
      bq[nt] = *(const h8*)&sB[(wn * 64 + nt * 16 + lane16) * 32 + quad * 8];
#pragma unroll
    for (int mt = 0; mt < 4; ++mt)
#pragma unroll
      for (int nt = 0; nt < 4; ++nt)
        acc[mt][nt] = __builtin_amdgcn_mfma_f32_16x16x32_f16(af[mt], bq[nt], acc[mt][nt], 0, 0, 0);
  }

#pragma unroll
  for (int nt = 0; nt < 4; ++nt) {
    int n = n0 + wn * 64 + nt * 16 + lane16;
    float bv = bias[n];
#pragma unroll
    for (int mt = 0; mt < 4; ++mt) {
      int mb = m0 + wm * 64 + mt * 16 + quad * 4;  // C/D: row = quad*4+i, col = lane16
#pragma unroll
      for (int i = 0; i < 4; ++i) {
        float v = acc[mt][nt][i] + bv;
        if (EPI == 0) {
          v = (v > 0.f) ? v : 0.01f * v;
          outh[(size_t)(mb + i) * N + n] = (_Float16)v;
        } else {
          outf[(size_t)(mb + i) * N + n] = v;
        }
      }
    }
  }
}

// ---------------- launch ----------------

extern "C" void kernel_launch(void* const* d_in, const int* in_sizes, int n_in,
                              void* d_out, int out_size, void* d_ws, size_t ws_size,
                              hipStream_t stream) {
  const float* mh  = (const float*)d_in[0];
  const float* eh  = (const float*)d_in[1];
  const float* sh  = (const float*)d_in[2];
  const int*   es  = (const int*)d_in[3];
  const int*   ed  = (const int*)d_in[4];
  const float* te  = (const float*)d_in[5];
  const float* lns = (const float*)d_in[6];
  const float* lnb = (const float*)d_in[7];
  const float* gw  = (const float*)d_in[8];   // [3][1024][1024]
  const float* gb  = (const float*)d_in[9];   // [3][1024]
  const float* fw  = (const float*)d_in[10];  // [1024][768]
  const float* fb  = (const float*)d_in[11];  // [768]
  float* out = (float*)d_out;                 // [128*50*768] f32
  int nE = in_sizes[3];

  char* p = (char*)d_ws;
  auto alloc = [&](size_t bytes) -> void* {
    void* r = (void*)p;
    p += (bytes + 255) & ~(size_t)255;
    return r;
  };
  _Float16* xbuf = (_Float16*)alloc((size_t)NN * DCOL * 2);
  _Float16* agg  = (_Float16*)alloc((size_t)NN * DCOL * 2);
  _Float16* wt   = (_Float16*)alloc((size_t)3 * 1024 * 1024 * 2);
  _Float16* wtfc = (_Float16*)alloc((size_t)768 * 1024 * 2);
  u32* deg_out = (u32*)alloc((size_t)NN * 4);   // these three stay contiguous
  u32* deg_in  = (u32*)alloc((size_t)NN * 4);   // (89600 B each, 256-aligned)
  u32* cursor  = (u32*)alloc((size_t)NN * 4);
  u32* csr_off = (u32*)alloc((size_t)(NN + 1) * 4);
  float* dvo = (float*)alloc((size_t)NN * 4);
  float* dvi = (float*)alloc((size_t)NN * 4);
  int* csr_src = (int*)alloc((size_t)nE * 4);

  hipMemsetAsync(deg_out, 0, (size_t)3 * NN * 4, stream);  // deg_out, deg_in, cursor

  int eb = (nE + 255) / 256;
  degree_k<<<eb, 256, 0, stream>>>(es, ed, deg_out, deg_in, nE);
  dinv_k<<<(NN + 255) / 256, 256, 0, stream>>>(deg_out, deg_in, dvo, dvi);
  scan_k<<<1, 1024, 0, stream>>>(deg_in, csr_off, NN);
  scatter_k<<<eb, 256, 0, stream>>>(es, ed, csr_off, cursor, csr_src, nE);
  ln_k<<<NN, 256, 0, stream>>>(mh, eh, sh, te, lns, lnb, xbuf);
  transpose_k<<<dim3(32, 32), 256, 0, stream>>>(gw + 0 * 1048576, wt + 0 * 1048576, 1024, 1024);
  transpose_k<<<dim3(32, 32), 256, 0, stream>>>(gw + 1 * 1048576, wt + 1 * 1048576, 1024, 1024);
  transpose_k<<<dim3(32, 32), 256, 0, stream>>>(gw + 2 * 1048576, wt + 2 * 1048576, 1024, 1024);
  transpose_k<<<dim3(24, 32), 256, 0, stream>>>(fw, wtfc, 1024, 768);

  // layer 0
  aggregate_k<0><<<NN, 256, 0, stream>>>(xbuf, csr_off, csr_src, dvo, dvi, agg);
  gemm_bt<0><<<dim3(8, 175), 256, 0, stream>>>(agg, wt + 0 * 1048576, gb + 0,    xbuf, nullptr, 1024, 1024);
  // layer 1
  aggregate_k<0><<<NN, 256, 0, stream>>>(xbuf, csr_off, csr_src, dvo, dvi, agg);
  gemm_bt<0><<<dim3(8, 175), 256, 0, stream>>>(agg, wt + 1 * 1048576, gb + 1024, xbuf, nullptr, 1024, 1024);
  // layer 2: only entity dst rows are ever consumed downstream -> compact 6400 rows
  aggregate_k<1><<<6400, 256, 0, stream>>>(xbuf, csr_off, csr_src, dvo, dvi, agg);
  gemm_bt<0><<<dim3(8, 50), 256, 0, stream>>>(agg, wt + 2 * 1048576, gb + 2048, xbuf, nullptr, 1024, 1024);
  // FC on compact entity rows -> d_out [6400][768] f32
  gemm_bt<1><<<dim3(6, 50), 256, 0, stream>>>(xbuf, wtfc, fb, nullptr, out, 768, 1024);
}